// Round 7
// baseline (258.972 us; speedup 1.0000x reference)
//
#include <hip/hip_runtime.h>
#include <math.h>
#include <stdint.h>

#define NA 32          // N_AGENTS
#define SD 2048        // STATE_DIM
#define BT 2048        // B = BS*T
#define NFRG 144       // col frags (2304 padded cols / 16); 128 agent + 12 tail + 4 pad

typedef float floatx4 __attribute__((ext_vector_type(4)));
typedef short bf16x8  __attribute__((ext_vector_type(8)));

__device__ __forceinline__ unsigned short f2bf(float f) {
    union { float f; uint32_t u; } v; v.f = f;
    uint32_t r = v.u + 0x7FFFu + ((v.u >> 16) & 1u);
    return (unsigned short)(r >> 16);
}

// ---- fragment layouts ----
// A-frag (stA):  elem((bt*64+kc)*512 + (quad*16+l16)*8 + j) = st[bt*16+l16][kc*32+quad*8+j]
// B-frag (Wswz): elem(((i*NFRG+f)*2+h)*512 + (quad*16+l16)*8 + j) = W[n=f*16+l16][k=i*64+h*32+quad*8+j]
// C-frag (Ycn):  elem((bt*NFRG+f)*256 + (quad*16+l16)*4 + r) = -Y[bt*16+quad*4+r][f*16+l16]

// ---------------- K0a: st -> A-fragment-order bf16 ----------------
__global__ __launch_bounds__(256) void k0_ast(const float* __restrict__ st,
                                              unsigned short* __restrict__ stA) {
    int idx = blockIdx.x * 256 + threadIdx.x;   // 2048*256 threads
    int m = idx >> 8, kg = idx & 255;           // kg = 8-elem group along k
    int k0 = kg * 8;
    const float* src = st + (size_t)m * SD + k0;
    float4 v0 = *(const float4*)src;
    float4 v1 = *(const float4*)(src + 4);
    int bt = m >> 4, l16 = m & 15, kc = kg >> 2, quad = kg & 3;
    unsigned short* dst = stA + ((size_t)bt * 64 + kc) * 512 + (quad * 16 + l16) * 8;
    ushort4 o0, o1;
    o0.x = f2bf(v0.x); o0.y = f2bf(v0.y); o0.z = f2bf(v0.z); o0.w = f2bf(v0.w);
    o1.x = f2bf(v1.x); o1.y = f2bf(v1.y); o1.z = f2bf(v1.z); o1.w = f2bf(v1.w);
    *(ushort4*)(dst)     = o0;
    *(ushort4*)(dst + 4) = o1;
}

// ---------------- K0b: weights -> B-fragment-order bf16 ----------------
__global__ __launch_bounds__(256) void k0_wswz(const float* __restrict__ Ww1,
                                               const float* __restrict__ Wwf,
                                               const float* __restrict__ Wb1,
                                               const float* __restrict__ Wv1,
                                               unsigned short* __restrict__ Wswz) {
    __shared__ float tile[32][33];
    const int n0 = blockIdx.x * 32;   // 72 tiles
    const int k0 = blockIdx.y * 32;   // 64 tiles
    const float* src; int ld = 64, nb = 0;
    if (n0 < 2048)      { src = Ww1; ld = 2048; nb = n0; }
    else if (n0 < 2112) { src = Wwf; nb = n0 - 2048; }
    else if (n0 < 2176) { src = Wb1; nb = n0 - 2112; }
    else if (n0 < 2240) { src = Wv1; nb = n0 - 2176; }
    else                { src = nullptr; }
    const int t = threadIdx.x;
    {
        int nl = t & 31, kl0 = t >> 5;
        #pragma unroll
        for (int r = 0; r < 4; r++) {
            int kl = kl0 + r * 8;
            tile[kl][nl] = src ? src[(size_t)(k0 + kl) * ld + nb + nl] : 0.f;
        }
    }
    __syncthreads();
    {
        int kl = t & 31, nl0 = t >> 5;
        #pragma unroll
        for (int r = 0; r < 4; r++) {
            int nl = nl0 + r * 8;
            int n = n0 + nl, k = k0 + kl;
            int f = n >> 4, l16 = n & 15;
            int i = k >> 6, kr = k & 63;
            int h = kr >> 5, quad = (kr & 31) >> 3, j = kr & 7;
            size_t off = (((size_t)i * NFRG + f) * 2 + h) * 512 + (quad * 16 + l16) * 8 + j;
            Wswz[off] = f2bf(tile[kl][nl]);
        }
    }
}

// ---------------- K0c: concat bias (padded) ----------------
__global__ void k0_bias(const float* __restrict__ bw1, const float* __restrict__ bwf,
                        const float* __restrict__ bb1, const float* __restrict__ bv1,
                        float* __restrict__ bcat) {
    int n = blockIdx.x * 256 + threadIdx.x;
    if (n >= NFRG * 16) return;
    float v = 0.f;
    if (n < 2048)      v = bw1[n];
    else if (n < 2112) v = bwf[n - 2048];
    else if (n < 2176) v = bb1[n - 2112];
    else if (n < 2240) v = bv1[n - 2176];
    bcat[n] = v;
}

// ---------------- K1: Ycn = -(st @ Wcat + bias), fragment layout ----------
// Register-streamed MFMA loop, software-pipelined one iteration: load
// kc+1's A/B frags into shadow regs before issuing kc's MFMAs.
__global__ __launch_bounds__(256) void k1_gemm(const unsigned short* __restrict__ stA,
                                               const unsigned short* __restrict__ Wswz,
                                               const float* __restrict__ bcat,
                                               float* __restrict__ Ycn)
{
    const int t = threadIdx.x;
    const int m0t = blockIdx.x * 4;   // btile base (64 rows)
    const int n0f = blockIdx.y * 8;   // frag base (128 cols)
    const int wid = t >> 6, lane = t & 63;
    const int wm = wid & 1, wn = wid >> 1;
    const int l16 = lane & 15;

    floatx4 acc[2][4];
    #pragma unroll
    for (int i = 0; i < 2; i++)
        #pragma unroll
        for (int j = 0; j < 4; j++) acc[i][j] = (floatx4)0.f;

    const unsigned short* Ap0 = stA + ((size_t)(m0t + wm * 2 + 0) * 64) * 512 + lane * 8;
    const unsigned short* Ap1 = stA + ((size_t)(m0t + wm * 2 + 1) * 64) * 512 + lane * 8;
    const unsigned short* Bbase = Wswz + ((size_t)(n0f + wn * 4) * 2) * 512 + lane * 8;
    // B addr for (kc): i=kc>>1, h=kc&1:  Bbase + ((i*NFRG*2) + h)*512, frag stride 1024

    bf16x8 a0c = *(const bf16x8*)(Ap0);
    bf16x8 a1c = *(const bf16x8*)(Ap1);
    bf16x8 bc[4];
    #pragma unroll
    for (int nf = 0; nf < 4; nf++)
        bc[nf] = *(const bf16x8*)(Bbase + (size_t)nf * 1024);

    for (int kc = 0; kc < 64; kc++) {
        bf16x8 a0n, a1n, bn[4];
        if (kc < 63) {
            const int kn = kc + 1;
            a0n = *(const bf16x8*)(Ap0 + (size_t)kn * 512);
            a1n = *(const bf16x8*)(Ap1 + (size_t)kn * 512);
            const unsigned short* Bp =
                Bbase + ((size_t)(kn >> 1) * NFRG * 2 + (kn & 1)) * 512;
            #pragma unroll
            for (int nf = 0; nf < 4; nf++)
                bn[nf] = *(const bf16x8*)(Bp + (size_t)nf * 1024);
        }
        #pragma unroll
        for (int nf = 0; nf < 4; nf++) {
            acc[0][nf] = __builtin_amdgcn_mfma_f32_16x16x32_bf16(a0c, bc[nf], acc[0][nf], 0, 0, 0);
            acc[1][nf] = __builtin_amdgcn_mfma_f32_16x16x32_bf16(a1c, bc[nf], acc[1][nf], 0, 0, 0);
        }
        a0c = a0n; a1c = a1n;
        #pragma unroll
        for (int nf = 0; nf < 4; nf++) bc[nf] = bn[nf];
    }

    #pragma unroll
    for (int mf = 0; mf < 2; mf++)
        #pragma unroll
        for (int nf = 0; nf < 4; nf++) {
            const int f  = n0f + wn * 4 + nf;
            const int bt = m0t + wm * 2 + mf;
            const float bias = bcat[f * 16 + l16];
            floatx4 o;
            #pragma unroll
            for (int r = 0; r < 4; r++) o[r] = -(acc[mf][nf][r] + bias);
            *(floatx4*)(Ycn + ((size_t)bt * NFRG + f) * 256 + lane * 4) = o;
        }
}

// ---------------- K3: q1[i][b] — 4 waves share one mask's weights --------
// block = (mask i, 4 consecutive b-tiles); wave w owns bt = bx*4+w. The 4
// waves stream IDENTICAL weight addresses (same i) in near-lockstep ->
// weights hit L1/L2 once per block instead of once per wave.
// C-init from Ycn (= -Y) so after MFMA: c = P - Y = -D.
__global__ __launch_bounds__(256) void k3_q1(
    const unsigned short* __restrict__ stA, const float* __restrict__ qs,
    const unsigned short* __restrict__ Wswz, const float* __restrict__ Wv2,
    const float* __restrict__ bv2, const float* __restrict__ Ycn,
    float* __restrict__ q1)
{
    const int i  = blockIdx.y;                 // mask 0..31
    const int t  = threadIdx.x;
    const int w  = t >> 6, lane = t & 63;
    const int bt = blockIdx.x * 4 + w;         // b tile 0..127
    const int quad = lane >> 4, l16 = lane & 15;

    __shared__ float qs_s[4][16][33];

    {
        int b = lane >> 2, a0 = (lane & 3) * 8;
        const float* src = qs + (size_t)(bt * 16 + b) * NA + a0;
        #pragma unroll
        for (int u = 0; u < 8; u++) qs_s[w][b][a0 + u] = src[u];
    }
    bf16x8 A0 = *(const bf16x8*)(stA + ((size_t)bt * 64 + 2 * i + 0) * 512 + lane * 8);
    bf16x8 A1 = *(const bf16x8*)(stA + ((size_t)bt * 64 + 2 * i + 1) * 512 + lane * 8);
    __syncthreads();

    floatx4 hid[4];
    #pragma unroll
    for (int nf = 0; nf < 4; nf++) hid[nf] = (floatx4)0.f;

    const float*          Yb = Ycn  + (size_t)bt * NFRG * 256;
    const unsigned short* Wb = Wswz + (size_t)i * NFRG * 1024;

    for (int a = 0; a < 32; a++) {
        const float*          yp = Yb + (size_t)(a * 4) * 256 + lane * 4;
        const unsigned short* wp = Wb + (size_t)(a * 4) * 1024 + lane * 8;
        floatx4 acc[4];
        #pragma unroll
        for (int nf = 0; nf < 4; nf++) acc[nf] = *(const floatx4*)(yp + nf * 256);
        #pragma unroll
        for (int nf = 0; nf < 4; nf++) {
            bf16x8 b0 = *(const bf16x8*)(wp + nf * 1024);
            bf16x8 b1 = *(const bf16x8*)(wp + nf * 1024 + 512);
            acc[nf] = __builtin_amdgcn_mfma_f32_16x16x32_bf16(A0, b0, acc[nf], 0, 0, 0);
            acc[nf] = __builtin_amdgcn_mfma_f32_16x16x32_bf16(A1, b1, acc[nf], 0, 0, 0);
        }
        float qv[4];
        #pragma unroll
        for (int r = 0; r < 4; r++) qv[r] = qs_s[w][quad * 4 + r][a];
        #pragma unroll
        for (int nf = 0; nf < 4; nf++)
            #pragma unroll
            for (int r = 0; r < 4; r++)
                hid[nf][r] += qv[r] * fabsf(acc[nf][r]);
    }

    // tail frags 128..139: wf(0-3) | b1(4-7) | v(8-11)
    floatx4 wff[4], b1f[4], vacc = (floatx4)0.f;
    #pragma unroll
    for (int nft = 0; nft < 12; nft++) {
        const int f = 128 + nft;
        floatx4 c = *(const floatx4*)(Yb + (size_t)f * 256 + lane * 4);
        const unsigned short* wp = Wb + (size_t)f * 1024 + lane * 8;
        c = __builtin_amdgcn_mfma_f32_16x16x32_bf16(A0, *(const bf16x8*)(wp),       c, 0, 0, 0);
        c = __builtin_amdgcn_mfma_f32_16x16x32_bf16(A1, *(const bf16x8*)(wp + 512), c, 0, 0, 0);
        if (nft < 4) {
            #pragma unroll
            for (int r = 0; r < 4; r++) wff[nft][r] = fabsf(c[r]);
        } else if (nft < 8) {
            #pragma unroll
            for (int r = 0; r < 4; r++) b1f[nft - 4][r] = -c[r];
        } else {
            float wv2 = Wv2[(nft - 8) * 16 + l16];
            #pragma unroll
            for (int r = 0; r < 4; r++) vacc[r] += fmaxf(-c[r], 0.f) * wv2;
        }
    }

    const float bv2v = bv2[0];
    #pragma unroll
    for (int r = 0; r < 4; r++) {
        float s = vacc[r];
        #pragma unroll
        for (int nf = 0; nf < 4; nf++) {
            float h = hid[nf][r] + b1f[nf][r];
            h = h > 0.f ? h : expm1f(h);
            s += h * wff[nf][r];
        }
        s += __shfl_xor(s, 1); s += __shfl_xor(s, 2);
        s += __shfl_xor(s, 4); s += __shfl_xor(s, 8);
        if (l16 == 0) q1[(size_t)i * BT + bt * 16 + quad * 4 + r] = s + bv2v;
    }
}

// ---------------- K4: q_tot, wc, final mix — fragment-layout consumer ----
// block = b-tile, 4 waves; wave w owns agents w*8..w*8+7 and 3 tail frags.
__global__ __launch_bounds__(256) void k4_final(
    const float* __restrict__ qs, const float* __restrict__ Ycn,
    const float* __restrict__ q1, const float* __restrict__ Wv2,
    const float* __restrict__ bv2, float* __restrict__ out)
{
    const int bt = blockIdx.x;
    __shared__ float qs_s[16][33];
    __shared__ float qw_s[16][33];
    __shared__ float hidp[4][16][64];
    __shared__ float wfb[16][64], b1b[16][64], vb[16][64];
    __shared__ float qt[16];

    const int t = threadIdx.x, w = t >> 6, lane = t & 63;
    const int quad = lane >> 4, l16 = lane & 15;
    const float bv2v = bv2[0];

    {
        int l = t * 2;
        float2 v = *(const float2*)&qs[(size_t)(bt * 16 + (l >> 5)) * NA + (l & 31)];
        qs_s[l >> 5][(l & 31) + 0] = v.x;
        qs_s[l >> 5][(l & 31) + 1] = v.y;
    }
    __syncthreads();

    const float* Yb = Ycn + (size_t)bt * NFRG * 256;

    // pass 1: hid with plain qs
    floatx4 hid[4];
    #pragma unroll
    for (int nf = 0; nf < 4; nf++) hid[nf] = (floatx4)0.f;
    for (int ia = 0; ia < 8; ia++) {
        const int a = w * 8 + ia;
        const float* yp = Yb + (size_t)(a * 4) * 256 + lane * 4;
        float qv[4];
        #pragma unroll
        for (int r = 0; r < 4; r++) qv[r] = qs_s[quad * 4 + r][a];
        #pragma unroll
        for (int nf = 0; nf < 4; nf++) {
            floatx4 c = *(const floatx4*)(yp + nf * 256);   // c = -Y
            #pragma unroll
            for (int r = 0; r < 4; r++) hid[nf][r] += qv[r] * fabsf(c[r]);
        }
    }
    #pragma unroll
    for (int nf = 0; nf < 4; nf++)
        #pragma unroll
        for (int r = 0; r < 4; r++)
            hidp[w][quad * 4 + r][nf * 16 + l16] = hid[nf][r];

    // tail frags: 3 per wave
    #pragma unroll
    for (int fi = 0; fi < 3; fi++) {
        const int nft = w * 3 + fi;
        floatx4 c = *(const floatx4*)(Yb + (size_t)(128 + nft) * 256 + lane * 4);
        const int e = (nft & 3) * 16 + l16;
        #pragma unroll
        for (int r = 0; r < 4; r++) {
            int b = quad * 4 + r;
            if (nft < 4)      wfb[b][e] = fabsf(c[r]);
            else if (nft < 8) b1b[b][e] = -c[r];
            else              vb[b][e]  = fmaxf(-c[r], 0.f) * Wv2[e];
        }
    }
    __syncthreads();

    // q_tot for rows w*4..w*4+3
    #pragma unroll
    for (int bb = 0; bb < 4; bb++) {
        int b = w * 4 + bb;
        float h = hidp[0][b][lane] + hidp[1][b][lane]
                + hidp[2][b][lane] + hidp[3][b][lane] + b1b[b][lane];
        h = h > 0.f ? h : expm1f(h);
        float val = h * wfb[b][lane] + vb[b][lane];
        #pragma unroll
        for (int off = 32; off > 0; off >>= 1) val += __shfl_xor(val, off);
        if (lane == 0) qt[b] = val + bv2v;
    }
    __syncthreads();

    // wc: thread (w,quad,l16) -> row rr = w*4+quad, agents 2*l16, 2*l16+1
    {
        const int rr = w * 4 + quad;
        float qtv = qt[rr];
        float d0 = fabsf(qtv - q1[(size_t)(2 * l16 + 0) * BT + bt * 16 + rr]);
        float d1 = fabsf(qtv - q1[(size_t)(2 * l16 + 1) * BT + bt * 16 + rr]);
        float ss = d0 * d0 + d1 * d1;
        ss += __shfl_xor(ss, 1); ss += __shfl_xor(ss, 2);
        ss += __shfl_xor(ss, 4); ss += __shfl_xor(ss, 8);
        float inv = 1.f / fmaxf(sqrtf(ss), 1e-12f);
        qw_s[rr][2 * l16 + 0] = qs_s[rr][2 * l16 + 0] * d0 * inv;
        qw_s[rr][2 * l16 + 1] = qs_s[rr][2 * l16 + 1] * d1 * inv;
    }
    __syncthreads();

    // pass 2: hid with qs*wc
    floatx4 hid2[4];
    #pragma unroll
    for (int nf = 0; nf < 4; nf++) hid2[nf] = (floatx4)0.f;
    for (int ia = 0; ia < 8; ia++) {
        const int a = w * 8 + ia;
        const float* yp = Yb + (size_t)(a * 4) * 256 + lane * 4;
        float qv[4];
        #pragma unroll
        for (int r = 0; r < 4; r++) qv[r] = qw_s[quad * 4 + r][a];
        #pragma unroll
        for (int nf = 0; nf < 4; nf++) {
            floatx4 c = *(const floatx4*)(yp + nf * 256);
            #pragma unroll
            for (int r = 0; r < 4; r++) hid2[nf][r] += qv[r] * fabsf(c[r]);
        }
    }
    #pragma unroll
    for (int nf = 0; nf < 4; nf++)
        #pragma unroll
        for (int r = 0; r < 4; r++)
            hidp[w][quad * 4 + r][nf * 16 + l16] = hid2[nf][r];
    __syncthreads();

    #pragma unroll
    for (int bb = 0; bb < 4; bb++) {
        int b = w * 4 + bb;
        float h = hidp[0][b][lane] + hidp[1][b][lane]
                + hidp[2][b][lane] + hidp[3][b][lane] + b1b[b][lane];
        h = h > 0.f ? h : expm1f(h);
        float val = h * wfb[b][lane] + vb[b][lane];
        #pragma unroll
        for (int off = 32; off > 0; off >>= 1) val += __shfl_xor(val, off);
        if (lane == 0) out[bt * 16 + b] = val + bv2v;
    }
}

extern "C" void kernel_launch(void* const* d_in, const int* in_sizes, int n_in,
                              void* d_out, int out_size, void* d_ws, size_t ws_size,
                              hipStream_t stream) {
    const float* qs  = (const float*)d_in[0];
    const float* st  = (const float*)d_in[1];
    const float* Ww1 = (const float*)d_in[2];
    const float* bw1 = (const float*)d_in[3];
    const float* Wwf = (const float*)d_in[4];
    const float* bwf = (const float*)d_in[5];
    const float* Wb1 = (const float*)d_in[6];
    const float* bb1 = (const float*)d_in[7];
    const float* Wv1 = (const float*)d_in[8];
    const float* bv1 = (const float*)d_in[9];
    const float* Wv2 = (const float*)d_in[10];
    const float* bv2 = (const float*)d_in[11];
    float* out = (float*)d_out;

    // workspace (~37 MB)
    float* Ycn           = (float*)d_ws;                           // 128*144*256 f32 = 18.87 MB
    unsigned short* stA  = (unsigned short*)(Ycn + (size_t)128 * NFRG * 256); // 8.39 MB
    unsigned short* Wswz = stA + (size_t)SD * SD;                  // 32*144*1024 bf16 = 9.44 MB
    float* bcat          = (float*)(Wswz + (size_t)32 * NFRG * 1024); // 2304 f32
    float* q1v           = bcat + NFRG * 16;                       // 32*2048 f32

    k0_ast <<<(SD * SD / 8 + 255) / 256, 256, 0, stream>>>(st, stA);
    k0_wswz<<<dim3(NFRG / 2, SD / 32), 256, 0, stream>>>(Ww1, Wwf, Wb1, Wv1, Wswz);
    k0_bias<<<(NFRG * 16 + 255) / 256, 256, 0, stream>>>(bw1, bwf, bb1, bv1, bcat);

    k1_gemm<<<dim3(BT / 64, NFRG / 8), 256, 0, stream>>>(stA, Wswz, bcat, Ycn);
    k3_q1  <<<dim3(BT / 64, NA), 256, 0, stream>>>(stA, qs, Wswz, Wv2, bv2, Ycn, q1v);
    k4_final<<<BT / 16, 256, 0, stream>>>(qs, Ycn, q1v, Wv2, bv2, out);
}

// Round 8
// 232.044 us; speedup vs baseline: 1.1160x; 1.1160x over previous
//
#include <hip/hip_runtime.h>
#include <math.h>
#include <stdint.h>

#define NA 32          // N_AGENTS
#define SD 2048        // STATE_DIM
#define BT 2048        // B = BS*T
#define NFRG 144       // col frags (2304 padded cols / 16); 128 agent + 12 tail + 4 pad

typedef float floatx4 __attribute__((ext_vector_type(4)));
typedef short bf16x8  __attribute__((ext_vector_type(8)));

__device__ __forceinline__ unsigned short f2bf(float f) {
    union { float f; uint32_t u; } v; v.f = f;
    uint32_t r = v.u + 0x7FFFu + ((v.u >> 16) & 1u);
    return (unsigned short)(r >> 16);
}

__device__ __forceinline__ floatx4 bf4_to_f4(ushort4 u) {
    union { uint32_t i; float f; } t;
    floatx4 r;
    t.i = (uint32_t)u.x << 16; r[0] = t.f;
    t.i = (uint32_t)u.y << 16; r[1] = t.f;
    t.i = (uint32_t)u.z << 16; r[2] = t.f;
    t.i = (uint32_t)u.w << 16; r[3] = t.f;
    return r;
}

// ---- fragment layouts ----
// A-frag (stA):  elem((bt*64+kc)*512 + (quad*16+l16)*8 + j) = st[bt*16+l16][kc*32+quad*8+j]
// B-frag (Wswz): elem(((i*NFRG+f)*2+h)*512 + (quad*16+l16)*8 + j) = W[n=f*16+l16][k=i*64+h*32+quad*8+j]
// C-frag (Ycn, bf16): elem((bt*NFRG+f)*256 + lane*4 + r) = bf16(-Y[bt*16+quad*4+r][f*16+l16])

// ---------------- K0a: st -> A-fragment-order bf16 ----------------
__global__ __launch_bounds__(256) void k0_ast(const float* __restrict__ st,
                                              unsigned short* __restrict__ stA) {
    int idx = blockIdx.x * 256 + threadIdx.x;   // 2048*256 threads
    int m = idx >> 8, kg = idx & 255;           // kg = 8-elem group along k
    int k0 = kg * 8;
    const float* src = st + (size_t)m * SD + k0;
    float4 v0 = *(const float4*)src;
    float4 v1 = *(const float4*)(src + 4);
    int bt = m >> 4, l16 = m & 15, kc = kg >> 2, quad = kg & 3;
    unsigned short* dst = stA + ((size_t)bt * 64 + kc) * 512 + (quad * 16 + l16) * 8;
    ushort4 o0, o1;
    o0.x = f2bf(v0.x); o0.y = f2bf(v0.y); o0.z = f2bf(v0.z); o0.w = f2bf(v0.w);
    o1.x = f2bf(v1.x); o1.y = f2bf(v1.y); o1.z = f2bf(v1.z); o1.w = f2bf(v1.w);
    *(ushort4*)(dst)     = o0;
    *(ushort4*)(dst + 4) = o1;
}

// ---------------- K0b: weights -> B-fragment-order bf16 ----------------
__global__ __launch_bounds__(256) void k0_wswz(const float* __restrict__ Ww1,
                                               const float* __restrict__ Wwf,
                                               const float* __restrict__ Wb1,
                                               const float* __restrict__ Wv1,
                                               unsigned short* __restrict__ Wswz) {
    __shared__ float tile[32][33];
    const int n0 = blockIdx.x * 32;   // 72 tiles
    const int k0 = blockIdx.y * 32;   // 64 tiles
    const float* src; int ld = 64, nb = 0;
    if (n0 < 2048)      { src = Ww1; ld = 2048; nb = n0; }
    else if (n0 < 2112) { src = Wwf; nb = n0 - 2048; }
    else if (n0 < 2176) { src = Wb1; nb = n0 - 2112; }
    else if (n0 < 2240) { src = Wv1; nb = n0 - 2176; }
    else                { src = nullptr; }
    const int t = threadIdx.x;
    {
        int nl = t & 31, kl0 = t >> 5;
        #pragma unroll
        for (int r = 0; r < 4; r++) {
            int kl = kl0 + r * 8;
            tile[kl][nl] = src ? src[(size_t)(k0 + kl) * ld + nb + nl] : 0.f;
        }
    }
    __syncthreads();
    {
        int kl = t & 31, nl0 = t >> 5;
        #pragma unroll
        for (int r = 0; r < 4; r++) {
            int nl = nl0 + r * 8;
            int n = n0 + nl, k = k0 + kl;
            int f = n >> 4, l16 = n & 15;
            int i = k >> 6, kr = k & 63;
            int h = kr >> 5, quad = (kr & 31) >> 3, j = kr & 7;
            size_t off = (((size_t)i * NFRG + f) * 2 + h) * 512 + (quad * 16 + l16) * 8 + j;
            Wswz[off] = f2bf(tile[kl][nl]);
        }
    }
}

// ---------------- K0c: concat bias (padded) ----------------
__global__ void k0_bias(const float* __restrict__ bw1, const float* __restrict__ bwf,
                        const float* __restrict__ bb1, const float* __restrict__ bv1,
                        float* __restrict__ bcat) {
    int n = blockIdx.x * 256 + threadIdx.x;
    if (n >= NFRG * 16) return;
    float v = 0.f;
    if (n < 2048)      v = bw1[n];
    else if (n < 2112) v = bwf[n - 2048];
    else if (n < 2176) v = bb1[n - 2112];
    else if (n < 2240) v = bv1[n - 2176];
    bcat[n] = v;
}

// ---------------- K1: Ycn = bf16(-(st @ Wcat + bias)), fragment layout ----
// Register-streamed MFMA loop, software-pipelined one iteration.
__global__ __launch_bounds__(256) void k1_gemm(const unsigned short* __restrict__ stA,
                                               const unsigned short* __restrict__ Wswz,
                                               const float* __restrict__ bcat,
                                               unsigned short* __restrict__ Ycn)
{
    const int t = threadIdx.x;
    const int m0t = blockIdx.x * 4;   // btile base (64 rows)
    const int n0f = blockIdx.y * 8;   // frag base (128 cols)
    const int wid = t >> 6, lane = t & 63;
    const int wm = wid & 1, wn = wid >> 1;
    const int l16 = lane & 15;

    floatx4 acc[2][4];
    #pragma unroll
    for (int i = 0; i < 2; i++)
        #pragma unroll
        for (int j = 0; j < 4; j++) acc[i][j] = (floatx4)0.f;

    const unsigned short* Ap0 = stA + ((size_t)(m0t + wm * 2 + 0) * 64) * 512 + lane * 8;
    const unsigned short* Ap1 = stA + ((size_t)(m0t + wm * 2 + 1) * 64) * 512 + lane * 8;
    const unsigned short* Bbase = Wswz + ((size_t)(n0f + wn * 4) * 2) * 512 + lane * 8;

    bf16x8 a0c = *(const bf16x8*)(Ap0);
    bf16x8 a1c = *(const bf16x8*)(Ap1);
    bf16x8 bc[4];
    #pragma unroll
    for (int nf = 0; nf < 4; nf++)
        bc[nf] = *(const bf16x8*)(Bbase + (size_t)nf * 1024);

    for (int kc = 0; kc < 64; kc++) {
        bf16x8 a0n, a1n, bn[4];
        if (kc < 63) {
            const int kn = kc + 1;
            a0n = *(const bf16x8*)(Ap0 + (size_t)kn * 512);
            a1n = *(const bf16x8*)(Ap1 + (size_t)kn * 512);
            const unsigned short* Bp =
                Bbase + ((size_t)(kn >> 1) * NFRG * 2 + (kn & 1)) * 512;
            #pragma unroll
            for (int nf = 0; nf < 4; nf++)
                bn[nf] = *(const bf16x8*)(Bp + (size_t)nf * 1024);
        }
        #pragma unroll
        for (int nf = 0; nf < 4; nf++) {
            acc[0][nf] = __builtin_amdgcn_mfma_f32_16x16x32_bf16(a0c, bc[nf], acc[0][nf], 0, 0, 0);
            acc[1][nf] = __builtin_amdgcn_mfma_f32_16x16x32_bf16(a1c, bc[nf], acc[1][nf], 0, 0, 0);
        }
        a0c = a0n; a1c = a1n;
        #pragma unroll
        for (int nf = 0; nf < 4; nf++) bc[nf] = bn[nf];
    }

    #pragma unroll
    for (int mf = 0; mf < 2; mf++)
        #pragma unroll
        for (int nf = 0; nf < 4; nf++) {
            const int f  = n0f + wn * 4 + nf;
            const int bt = m0t + wm * 2 + mf;
            const float bias = bcat[f * 16 + l16];
            ushort4 o;
            o.x = f2bf(-(acc[mf][nf][0] + bias));
            o.y = f2bf(-(acc[mf][nf][1] + bias));
            o.z = f2bf(-(acc[mf][nf][2] + bias));
            o.w = f2bf(-(acc[mf][nf][3] + bias));
            *(ushort4*)(Ycn + ((size_t)bt * NFRG + f) * 256 + lane * 4) = o;
        }
}

// ---------------- K3: q1[i][b] — single wave, 2 b-tiles serially --------
// Weights for each agent loaded once (one-deep prefetch), applied to both
// tiles; independent waves (no barriers). C-init from bf16 Ycn (= -Y) so
// after MFMA: c = P - Y = -D.
__global__ __launch_bounds__(64) void k3_q1(
    const unsigned short* __restrict__ stA, const float* __restrict__ qs,
    const unsigned short* __restrict__ Wswz, const float* __restrict__ Wv2,
    const float* __restrict__ bv2, const unsigned short* __restrict__ Ycn,
    float* __restrict__ q1)
{
    const int pb = blockIdx.x;        // b-tile pair 0..63
    const int i  = blockIdx.y;        // mask 0..31
    __shared__ float qs_s[2][16][33];

    const int t = threadIdx.x;        // == lane
    const int quad = t >> 4, l16 = t & 15;

    #pragma unroll
    for (int p = 0; p < 2; p++) {
        int b = t >> 2, a0 = (t & 3) * 8;
        const float* src = qs + (size_t)((pb * 2 + p) * 16 + b) * NA + a0;
        #pragma unroll
        for (int u = 0; u < 8; u++) qs_s[p][b][a0 + u] = src[u];
    }
    bf16x8 A[2][2];
    #pragma unroll
    for (int p = 0; p < 2; p++)
        #pragma unroll
        for (int h = 0; h < 2; h++)
            A[p][h] = *(const bf16x8*)(stA + ((size_t)(pb * 2 + p) * 64 + 2 * i + h) * 512 + t * 8);
    __syncthreads();

    floatx4 hid[2][4];
    #pragma unroll
    for (int p = 0; p < 2; p++)
        #pragma unroll
        for (int nf = 0; nf < 4; nf++) hid[p][nf] = (floatx4)0.f;

    const unsigned short* Wb = Wswz + (size_t)i * NFRG * 1024;
    const unsigned short* Y0 = Ycn + (size_t)(pb * 2 + 0) * NFRG * 256;
    const unsigned short* Y1 = Ycn + (size_t)(pb * 2 + 1) * NFRG * 256;

    bf16x8 wc_[8];
    {
        const unsigned short* wp = Wb + t * 8;
        #pragma unroll
        for (int nf = 0; nf < 4; nf++) {
            wc_[nf * 2 + 0] = *(const bf16x8*)(wp + (size_t)nf * 1024);
            wc_[nf * 2 + 1] = *(const bf16x8*)(wp + (size_t)nf * 1024 + 512);
        }
    }

    for (int a = 0; a < 32; a++) {
        bf16x8 wn_[8];
        if (a < 31) {
            const unsigned short* wp = Wb + (size_t)((a + 1) * 4) * 1024 + t * 8;
            #pragma unroll
            for (int nf = 0; nf < 4; nf++) {
                wn_[nf * 2 + 0] = *(const bf16x8*)(wp + (size_t)nf * 1024);
                wn_[nf * 2 + 1] = *(const bf16x8*)(wp + (size_t)nf * 1024 + 512);
            }
        }
        const unsigned short* yp0 = Y0 + (size_t)(a * 4) * 256 + t * 4;
        const unsigned short* yp1 = Y1 + (size_t)(a * 4) * 256 + t * 4;
        floatx4 acc0[4], acc1[4];
        #pragma unroll
        for (int nf = 0; nf < 4; nf++) {
            acc0[nf] = bf4_to_f4(*(const ushort4*)(yp0 + nf * 256));
            acc1[nf] = bf4_to_f4(*(const ushort4*)(yp1 + nf * 256));
        }
        #pragma unroll
        for (int nf = 0; nf < 4; nf++) {
            acc0[nf] = __builtin_amdgcn_mfma_f32_16x16x32_bf16(A[0][0], wc_[nf*2+0], acc0[nf], 0, 0, 0);
            acc0[nf] = __builtin_amdgcn_mfma_f32_16x16x32_bf16(A[0][1], wc_[nf*2+1], acc0[nf], 0, 0, 0);
            acc1[nf] = __builtin_amdgcn_mfma_f32_16x16x32_bf16(A[1][0], wc_[nf*2+0], acc1[nf], 0, 0, 0);
            acc1[nf] = __builtin_amdgcn_mfma_f32_16x16x32_bf16(A[1][1], wc_[nf*2+1], acc1[nf], 0, 0, 0);
        }
        float qv0[4], qv1[4];
        #pragma unroll
        for (int r = 0; r < 4; r++) {
            qv0[r] = qs_s[0][quad * 4 + r][a];
            qv1[r] = qs_s[1][quad * 4 + r][a];
        }
        #pragma unroll
        for (int nf = 0; nf < 4; nf++)
            #pragma unroll
            for (int r = 0; r < 4; r++) {
                hid[0][nf][r] += qv0[r] * fabsf(acc0[nf][r]);
                hid[1][nf][r] += qv1[r] * fabsf(acc1[nf][r]);
            }
        #pragma unroll
        for (int u = 0; u < 8; u++) wc_[u] = wn_[u];
    }

    // tail frags 128..139: wf(0-3) | b1(4-7) | v(8-11), both tiles
    const float bv2v = bv2[0];
    floatx4 wff[2][4], b1f[2][4], vacc[2];
    vacc[0] = (floatx4)0.f; vacc[1] = (floatx4)0.f;
    #pragma unroll
    for (int nft = 0; nft < 12; nft++) {
        const int f = 128 + nft;
        const unsigned short* wp = Wb + (size_t)f * 1024 + t * 8;
        bf16x8 tb0 = *(const bf16x8*)(wp);
        bf16x8 tb1 = *(const bf16x8*)(wp + 512);
        #pragma unroll
        for (int p = 0; p < 2; p++) {
            const unsigned short* yp = (p == 0 ? Y0 : Y1) + (size_t)f * 256 + t * 4;
            floatx4 c = bf4_to_f4(*(const ushort4*)(yp));
            c = __builtin_amdgcn_mfma_f32_16x16x32_bf16(A[p][0], tb0, c, 0, 0, 0);
            c = __builtin_amdgcn_mfma_f32_16x16x32_bf16(A[p][1], tb1, c, 0, 0, 0);
            if (nft < 4) {
                #pragma unroll
                for (int r = 0; r < 4; r++) wff[p][nft][r] = fabsf(c[r]);
            } else if (nft < 8) {
                #pragma unroll
                for (int r = 0; r < 4; r++) b1f[p][nft - 4][r] = -c[r];
            } else {
                float wv2 = Wv2[(nft - 8) * 16 + l16];
                #pragma unroll
                for (int r = 0; r < 4; r++) vacc[p][r] += fmaxf(-c[r], 0.f) * wv2;
            }
        }
    }

    #pragma unroll
    for (int p = 0; p < 2; p++)
        #pragma unroll
        for (int r = 0; r < 4; r++) {
            float s = vacc[p][r];
            #pragma unroll
            for (int nf = 0; nf < 4; nf++) {
                float h = hid[p][nf][r] + b1f[p][nf][r];
                h = h > 0.f ? h : expm1f(h);
                s += h * wff[p][nf][r];
            }
            s += __shfl_xor(s, 1); s += __shfl_xor(s, 2);
            s += __shfl_xor(s, 4); s += __shfl_xor(s, 8);
            if (l16 == 0)
                q1[(size_t)i * BT + (pb * 2 + p) * 16 + quad * 4 + r] = s + bv2v;
        }
}

// ---------------- K4: q_tot, wc, final mix — bf16 fragment consumer ------
// block = b-tile, 4 waves; wave w owns agents w*8..w*8+7 and 3 tail frags.
__global__ __launch_bounds__(256) void k4_final(
    const float* __restrict__ qs, const unsigned short* __restrict__ Ycn,
    const float* __restrict__ q1, const float* __restrict__ Wv2,
    const float* __restrict__ bv2, float* __restrict__ out)
{
    const int bt = blockIdx.x;
    __shared__ float qs_s[16][33];
    __shared__ float qw_s[16][33];
    __shared__ float hidp[4][16][64];
    __shared__ float wfb[16][64], b1b[16][64], vb[16][64];
    __shared__ float qt[16];

    const int t = threadIdx.x, w = t >> 6, lane = t & 63;
    const int quad = lane >> 4, l16 = lane & 15;
    const float bv2v = bv2[0];

    {
        int l = t * 2;
        float2 v = *(const float2*)&qs[(size_t)(bt * 16 + (l >> 5)) * NA + (l & 31)];
        qs_s[l >> 5][(l & 31) + 0] = v.x;
        qs_s[l >> 5][(l & 31) + 1] = v.y;
    }
    __syncthreads();

    const unsigned short* Yb = Ycn + (size_t)bt * NFRG * 256;

    // pass 1: hid with plain qs
    floatx4 hid[4];
    #pragma unroll
    for (int nf = 0; nf < 4; nf++) hid[nf] = (floatx4)0.f;
    for (int ia = 0; ia < 8; ia++) {
        const int a = w * 8 + ia;
        const unsigned short* yp = Yb + (size_t)(a * 4) * 256 + lane * 4;
        float qv[4];
        #pragma unroll
        for (int r = 0; r < 4; r++) qv[r] = qs_s[quad * 4 + r][a];
        #pragma unroll
        for (int nf = 0; nf < 4; nf++) {
            floatx4 c = bf4_to_f4(*(const ushort4*)(yp + nf * 256));   // c = -Y
            #pragma unroll
            for (int r = 0; r < 4; r++) hid[nf][r] += qv[r] * fabsf(c[r]);
        }
    }
    #pragma unroll
    for (int nf = 0; nf < 4; nf++)
        #pragma unroll
        for (int r = 0; r < 4; r++)
            hidp[w][quad * 4 + r][nf * 16 + l16] = hid[nf][r];

    // tail frags: 3 per wave
    #pragma unroll
    for (int fi = 0; fi < 3; fi++) {
        const int nft = w * 3 + fi;
        floatx4 c = bf4_to_f4(*(const ushort4*)(Yb + (size_t)(128 + nft) * 256 + lane * 4));
        const int e = (nft & 3) * 16 + l16;
        #pragma unroll
        for (int r = 0; r < 4; r++) {
            int b = quad * 4 + r;
            if (nft < 4)      wfb[b][e] = fabsf(c[r]);
            else if (nft < 8) b1b[b][e] = -c[r];
            else              vb[b][e]  = fmaxf(-c[r], 0.f) * Wv2[e];
        }
    }
    __syncthreads();

    // q_tot for rows w*4..w*4+3
    #pragma unroll
    for (int bb = 0; bb < 4; bb++) {
        int b = w * 4 + bb;
        float h = hidp[0][b][lane] + hidp[1][b][lane]
                + hidp[2][b][lane] + hidp[3][b][lane] + b1b[b][lane];
        h = h > 0.f ? h : expm1f(h);
        float val = h * wfb[b][lane] + vb[b][lane];
        #pragma unroll
        for (int off = 32; off > 0; off >>= 1) val += __shfl_xor(val, off);
        if (lane == 0) qt[b] = val + bv2v;
    }
    __syncthreads();

    // wc: thread (w,quad,l16) -> row rr = w*4+quad, agents 2*l16, 2*l16+1
    {
        const int rr = w * 4 + quad;
        float qtv = qt[rr];
        float d0 = fabsf(qtv - q1[(size_t)(2 * l16 + 0) * BT + bt * 16 + rr]);
        float d1 = fabsf(qtv - q1[(size_t)(2 * l16 + 1) * BT + bt * 16 + rr]);
        float ss = d0 * d0 + d1 * d1;
        ss += __shfl_xor(ss, 1); ss += __shfl_xor(ss, 2);
        ss += __shfl_xor(ss, 4); ss += __shfl_xor(ss, 8);
        float inv = 1.f / fmaxf(sqrtf(ss), 1e-12f);
        qw_s[rr][2 * l16 + 0] = qs_s[rr][2 * l16 + 0] * d0 * inv;
        qw_s[rr][2 * l16 + 1] = qs_s[rr][2 * l16 + 1] * d1 * inv;
    }
    __syncthreads();

    // pass 2: hid with qs*wc
    floatx4 hid2[4];
    #pragma unroll
    for (int nf = 0; nf < 4; nf++) hid2[nf] = (floatx4)0.f;
    for (int ia = 0; ia < 8; ia++) {
        const int a = w * 8 + ia;
        const unsigned short* yp = Yb + (size_t)(a * 4) * 256 + lane * 4;
        float qv[4];
        #pragma unroll
        for (int r = 0; r < 4; r++) qv[r] = qw_s[quad * 4 + r][a];
        #pragma unroll
        for (int nf = 0; nf < 4; nf++) {
            floatx4 c = bf4_to_f4(*(const ushort4*)(yp + nf * 256));
            #pragma unroll
            for (int r = 0; r < 4; r++) hid2[nf][r] += qv[r] * fabsf(c[r]);
        }
    }
    #pragma unroll
    for (int nf = 0; nf < 4; nf++)
        #pragma unroll
        for (int r = 0; r < 4; r++)
            hidp[w][quad * 4 + r][nf * 16 + l16] = hid2[nf][r];
    __syncthreads();

    #pragma unroll
    for (int bb = 0; bb < 4; bb++) {
        int b = w * 4 + bb;
        float h = hidp[0][b][lane] + hidp[1][b][lane]
                + hidp[2][b][lane] + hidp[3][b][lane] + b1b[b][lane];
        h = h > 0.f ? h : expm1f(h);
        float val = h * wfb[b][lane] + vb[b][lane];
        #pragma unroll
        for (int off = 32; off > 0; off >>= 1) val += __shfl_xor(val, off);
        if (lane == 0) out[bt * 16 + b] = val + bv2v;
    }
}

extern "C" void kernel_launch(void* const* d_in, const int* in_sizes, int n_in,
                              void* d_out, int out_size, void* d_ws, size_t ws_size,
                              hipStream_t stream) {
    const float* qs  = (const float*)d_in[0];
    const float* st  = (const float*)d_in[1];
    const float* Ww1 = (const float*)d_in[2];
    const float* bw1 = (const float*)d_in[3];
    const float* Wwf = (const float*)d_in[4];
    const float* bwf = (const float*)d_in[5];
    const float* Wb1 = (const float*)d_in[6];
    const float* bb1 = (const float*)d_in[7];
    const float* Wv1 = (const float*)d_in[8];
    const float* bv1 = (const float*)d_in[9];
    const float* Wv2 = (const float*)d_in[10];
    const float* bv2 = (const float*)d_in[11];
    float* out = (float*)d_out;

    // workspace (~28 MB)
    unsigned short* Ycn  = (unsigned short*)d_ws;                  // 128*144*256 bf16 = 9.44 MB
    unsigned short* stA  = Ycn + (size_t)128 * NFRG * 256;         // 8.39 MB
    unsigned short* Wswz = stA + (size_t)SD * SD;                  // 32*144*1024 bf16 = 9.44 MB
    float* bcat          = (float*)(Wswz + (size_t)32 * NFRG * 1024); // 2304 f32
    float* q1v           = bcat + NFRG * 16;                       // 32*2048 f32

    k0_ast <<<(SD * SD / 8 + 255) / 256, 256, 0, stream>>>(st, stA);
    k0_wswz<<<dim3(NFRG / 2, SD / 32), 256, 0, stream>>>(Ww1, Wwf, Wb1, Wv1, Wswz);
    k0_bias<<<(NFRG * 16 + 255) / 256, 256, 0, stream>>>(bw1, bwf, bb1, bv1, bcat);

    k1_gemm<<<dim3(BT / 64, NFRG / 8), 256, 0, stream>>>(stA, Wswz, bcat, Ycn);
    k3_q1  <<<dim3(BT / 32, NA), 64, 0, stream>>>(stA, qs, Wswz, Wv2, bv2, Ycn, q1v);
    k4_final<<<BT / 16, 256, 0, stream>>>(qs, Ycn, q1v, Wv2, bv2, out);
}

// Round 9
// 231.794 us; speedup vs baseline: 1.1172x; 1.0011x over previous
//
#include <hip/hip_runtime.h>
#include <math.h>
#include <stdint.h>

#define NA 32          // N_AGENTS
#define SD 2048        // STATE_DIM
#define BT 2048        // B = BS*T
#define NFRG 144       // col frags (2304 padded cols / 16); 128 agent + 12 tail + 4 pad

typedef float floatx4 __attribute__((ext_vector_type(4)));
typedef short bf16x8  __attribute__((ext_vector_type(8)));

__device__ __forceinline__ unsigned short f2bf(float f) {
    union { float f; uint32_t u; } v; v.f = f;
    uint32_t r = v.u + 0x7FFFu + ((v.u >> 16) & 1u);
    return (unsigned short)(r >> 16);
}

__device__ __forceinline__ floatx4 bf4_to_f4(ushort4 u) {
    union { uint32_t i; float f; } t;
    floatx4 r;
    t.i = (uint32_t)u.x << 16; r[0] = t.f;
    t.i = (uint32_t)u.y << 16; r[1] = t.f;
    t.i = (uint32_t)u.z << 16; r[2] = t.f;
    t.i = (uint32_t)u.w << 16; r[3] = t.f;
    return r;
}

// ---- fragment layouts ----
// A-frag (stA):  elem((bt*64+kc)*512 + (quad*16+l16)*8 + j) = st[bt*16+l16][kc*32+quad*8+j]
// B-frag (Wswz): elem(((i*NFRG+f)*2+h)*512 + (quad*16+l16)*8 + j) = W[n=f*16+l16][k=i*64+h*32+quad*8+j]
// C-frag (Ycn, bf16): elem((bt*NFRG+f)*256 + (quad*16+l16)*4 + r) = bf16(-Y[bt*16+quad*4+r][f*16+l16])

// ---------------- K0a: st -> A-fragment-order bf16 (coalesced writes) ----
// One wave per (bt, kc) fragment: lane l writes its 16B chunk contiguously.
__global__ __launch_bounds__(256) void k0_ast(const float* __restrict__ st,
                                              unsigned short* __restrict__ stA) {
    const int t  = threadIdx.x;
    const int kc = blockIdx.x * 4 + (t >> 6);   // 0..63
    const int bt = blockIdx.y;                  // 0..127
    const int l  = t & 63;
    const int quad = l >> 4, l16 = l & 15;
    const float* src = st + (size_t)(bt * 16 + l16) * SD + kc * 32 + quad * 8;
    float4 v0 = *(const float4*)(src);
    float4 v1 = *(const float4*)(src + 4);
    ushort4 o0, o1;
    o0.x = f2bf(v0.x); o0.y = f2bf(v0.y); o0.z = f2bf(v0.z); o0.w = f2bf(v0.w);
    o1.x = f2bf(v1.x); o1.y = f2bf(v1.y); o1.z = f2bf(v1.z); o1.w = f2bf(v1.w);
    unsigned short* dst = stA + ((size_t)bt * 64 + kc) * 512 + l * 8;
    *(ushort4*)(dst)     = o0;
    *(ushort4*)(dst + 4) = o1;
}

// ---------------- K0b: weights -> B-frag order (coalesced writes) --------
// Wave-uniform (f,h); lane l = quad*16+l16 writes 16B contiguous. Reads:
// 16 lanes of a quad read 16 consecutive n at same k -> 64B segments.
__global__ __launch_bounds__(256) void k0_wswz(const float* __restrict__ Ww1,
                                               const float* __restrict__ Wwf,
                                               const float* __restrict__ Wb1,
                                               const float* __restrict__ Wv1,
                                               unsigned short* __restrict__ Wswz) {
    const int t = threadIdx.x;
    const int i = blockIdx.y;                   // k-chunk 0..31
    const int f = blockIdx.x * 2 + (t >> 7);    // frag 0..143
    const int h = (t >> 6) & 1;
    const int l = t & 63;
    const int quad = l >> 4, l16 = l & 15;
    const int n = f * 16 + l16;

    const float* src; int ld, nr = 0;
    if (f < 128)      { src = Ww1; ld = 2048; nr = n; }
    else if (f < 132) { src = Wwf; ld = 64;   nr = n - 2048; }
    else if (f < 136) { src = Wb1; ld = 64;   nr = n - 2112; }
    else if (f < 140) { src = Wv1; ld = 64;   nr = n - 2176; }
    else              { src = nullptr; ld = 64; }

    const int k0 = i * 64 + h * 32 + quad * 8;
    unsigned short vals[8];
    #pragma unroll
    for (int j = 0; j < 8; j++)
        vals[j] = src ? f2bf(src[(size_t)(k0 + j) * ld + nr]) : (unsigned short)0;

    unsigned short* dst = Wswz + (((size_t)i * NFRG + f) * 2 + h) * 512 + l * 8;
    ushort4 o0 = {vals[0], vals[1], vals[2], vals[3]};
    ushort4 o1 = {vals[4], vals[5], vals[6], vals[7]};
    *(ushort4*)(dst)     = o0;
    *(ushort4*)(dst + 4) = o1;
}

// ---------------- K0c: concat bias (padded) ----------------
__global__ void k0_bias(const float* __restrict__ bw1, const float* __restrict__ bwf,
                        const float* __restrict__ bb1, const float* __restrict__ bv1,
                        float* __restrict__ bcat) {
    int n = blockIdx.x * 256 + threadIdx.x;
    if (n >= NFRG * 16) return;
    float v = 0.f;
    if (n < 2048)      v = bw1[n];
    else if (n < 2112) v = bwf[n - 2048];
    else if (n < 2176) v = bb1[n - 2112];
    else if (n < 2240) v = bv1[n - 2176];
    bcat[n] = v;
}

// ---------------- K1: Ycn = bf16(-(st @ Wcat + bias)), fragment layout ----
// Register-streamed MFMA loop, software-pipelined one iteration.
__global__ __launch_bounds__(256) void k1_gemm(const unsigned short* __restrict__ stA,
                                               const unsigned short* __restrict__ Wswz,
                                               const float* __restrict__ bcat,
                                               unsigned short* __restrict__ Ycn)
{
    const int t = threadIdx.x;
    const int m0t = blockIdx.x * 4;   // btile base (64 rows)
    const int n0f = blockIdx.y * 8;   // frag base (128 cols)
    const int wid = t >> 6, lane = t & 63;
    const int wm = wid & 1, wn = wid >> 1;
    const int l16 = lane & 15;

    floatx4 acc[2][4];
    #pragma unroll
    for (int i = 0; i < 2; i++)
        #pragma unroll
        for (int j = 0; j < 4; j++) acc[i][j] = (floatx4)0.f;

    const unsigned short* Ap0 = stA + ((size_t)(m0t + wm * 2 + 0) * 64) * 512 + lane * 8;
    const unsigned short* Ap1 = stA + ((size_t)(m0t + wm * 2 + 1) * 64) * 512 + lane * 8;
    const unsigned short* Bbase = Wswz + ((size_t)(n0f + wn * 4) * 2) * 512 + lane * 8;

    bf16x8 a0c = *(const bf16x8*)(Ap0);
    bf16x8 a1c = *(const bf16x8*)(Ap1);
    bf16x8 bc[4];
    #pragma unroll
    for (int nf = 0; nf < 4; nf++)
        bc[nf] = *(const bf16x8*)(Bbase + (size_t)nf * 1024);

    for (int kc = 0; kc < 64; kc++) {
        bf16x8 a0n, a1n, bn[4];
        if (kc < 63) {
            const int kn = kc + 1;
            a0n = *(const bf16x8*)(Ap0 + (size_t)kn * 512);
            a1n = *(const bf16x8*)(Ap1 + (size_t)kn * 512);
            const unsigned short* Bp =
                Bbase + ((size_t)(kn >> 1) * NFRG * 2 + (kn & 1)) * 512;
            #pragma unroll
            for (int nf = 0; nf < 4; nf++)
                bn[nf] = *(const bf16x8*)(Bp + (size_t)nf * 1024);
        }
        #pragma unroll
        for (int nf = 0; nf < 4; nf++) {
            acc[0][nf] = __builtin_amdgcn_mfma_f32_16x16x32_bf16(a0c, bc[nf], acc[0][nf], 0, 0, 0);
            acc[1][nf] = __builtin_amdgcn_mfma_f32_16x16x32_bf16(a1c, bc[nf], acc[1][nf], 0, 0, 0);
        }
        a0c = a0n; a1c = a1n;
        #pragma unroll
        for (int nf = 0; nf < 4; nf++) bc[nf] = bn[nf];
    }

    #pragma unroll
    for (int mf = 0; mf < 2; mf++)
        #pragma unroll
        for (int nf = 0; nf < 4; nf++) {
            const int f  = n0f + wn * 4 + nf;
            const int bt = m0t + wm * 2 + mf;
            const float bias = bcat[f * 16 + l16];
            ushort4 o;
            o.x = f2bf(-(acc[mf][nf][0] + bias));
            o.y = f2bf(-(acc[mf][nf][1] + bias));
            o.z = f2bf(-(acc[mf][nf][2] + bias));
            o.w = f2bf(-(acc[mf][nf][3] + bias));
            *(ushort4*)(Ycn + ((size_t)bt * NFRG + f) * 256 + lane * 4) = o;
        }
}

// ---------------- K3: q1[i][b] — R6 single-wave structure, bf16 Ycn ------
// 4096 independent waves; all loads contiguous 16B/8B per lane.
// C-init from bf16 Ycn (= -Y) so after MFMA: c = P - Y = -D.
__global__ __launch_bounds__(64) void k3_q1(
    const unsigned short* __restrict__ stA, const float* __restrict__ qs,
    const unsigned short* __restrict__ Wswz, const float* __restrict__ Wv2,
    const float* __restrict__ bv2, const unsigned short* __restrict__ Ycn,
    float* __restrict__ q1)
{
    const int bt = blockIdx.x;        // b tile 0..127
    const int i  = blockIdx.y;        // mask 0..31
    __shared__ float qs_s[16][33];

    const int t = threadIdx.x;        // == lane
    const int quad = t >> 4, l16 = t & 15;

    {
        int b = t >> 2, a0 = (t & 3) * 8;
        const float* src = qs + (size_t)(bt * 16 + b) * NA + a0;
        #pragma unroll
        for (int u = 0; u < 8; u++) qs_s[b][a0 + u] = src[u];
    }
    bf16x8 A0 = *(const bf16x8*)(stA + ((size_t)bt * 64 + 2 * i + 0) * 512 + t * 8);
    bf16x8 A1 = *(const bf16x8*)(stA + ((size_t)bt * 64 + 2 * i + 1) * 512 + t * 8);
    __syncthreads();

    floatx4 hid[4];
    #pragma unroll
    for (int nf = 0; nf < 4; nf++) hid[nf] = (floatx4)0.f;

    const unsigned short* Yb = Ycn  + (size_t)bt * NFRG * 256;
    const unsigned short* Wb = Wswz + (size_t)i * NFRG * 1024;

    for (int a = 0; a < 32; a++) {
        const unsigned short* yp = Yb + (size_t)(a * 4) * 256 + t * 4;
        const unsigned short* wp = Wb + (size_t)(a * 4) * 1024 + t * 8;
        floatx4 acc[4];
        #pragma unroll
        for (int nf = 0; nf < 4; nf++)
            acc[nf] = bf4_to_f4(*(const ushort4*)(yp + nf * 256));
        #pragma unroll
        for (int nf = 0; nf < 4; nf++) {
            bf16x8 b0 = *(const bf16x8*)(wp + nf * 1024);
            bf16x8 b1 = *(const bf16x8*)(wp + nf * 1024 + 512);
            acc[nf] = __builtin_amdgcn_mfma_f32_16x16x32_bf16(A0, b0, acc[nf], 0, 0, 0);
            acc[nf] = __builtin_amdgcn_mfma_f32_16x16x32_bf16(A1, b1, acc[nf], 0, 0, 0);
        }
        float qv[4];
        #pragma unroll
        for (int r = 0; r < 4; r++) qv[r] = qs_s[quad * 4 + r][a];
        #pragma unroll
        for (int nf = 0; nf < 4; nf++)
            #pragma unroll
            for (int r = 0; r < 4; r++)
                hid[nf][r] += qv[r] * fabsf(acc[nf][r]);
    }

    // tail frags 128..139: wf(0-3) | b1(4-7) | v(8-11)
    floatx4 wff[4], b1f[4], vacc = (floatx4)0.f;
    #pragma unroll
    for (int nft = 0; nft < 12; nft++) {
        const int f = 128 + nft;
        floatx4 c = bf4_to_f4(*(const ushort4*)(Yb + (size_t)f * 256 + t * 4));
        const unsigned short* wp = Wb + (size_t)f * 1024 + t * 8;
        c = __builtin_amdgcn_mfma_f32_16x16x32_bf16(A0, *(const bf16x8*)(wp),       c, 0, 0, 0);
        c = __builtin_amdgcn_mfma_f32_16x16x32_bf16(A1, *(const bf16x8*)(wp + 512), c, 0, 0, 0);
        if (nft < 4) {
            #pragma unroll
            for (int r = 0; r < 4; r++) wff[nft][r] = fabsf(c[r]);
        } else if (nft < 8) {
            #pragma unroll
            for (int r = 0; r < 4; r++) b1f[nft - 4][r] = -c[r];
        } else {
            float wv2 = Wv2[(nft - 8) * 16 + l16];
            #pragma unroll
            for (int r = 0; r < 4; r++) vacc[r] += fmaxf(-c[r], 0.f) * wv2;
        }
    }

    const float bv2v = bv2[0];
    #pragma unroll
    for (int r = 0; r < 4; r++) {
        float s = vacc[r];
        #pragma unroll
        for (int nf = 0; nf < 4; nf++) {
            float h = hid[nf][r] + b1f[nf][r];
            h = h > 0.f ? h : expm1f(h);
            s += h * wff[nf][r];
        }
        s += __shfl_xor(s, 1); s += __shfl_xor(s, 2);
        s += __shfl_xor(s, 4); s += __shfl_xor(s, 8);
        if (l16 == 0) q1[(size_t)i * BT + bt * 16 + quad * 4 + r] = s + bv2v;
    }
}

// ---------------- K4: q_tot, wc, final mix — bf16 fragment consumer ------
__global__ __launch_bounds__(256) void k4_final(
    const float* __restrict__ qs, const unsigned short* __restrict__ Ycn,
    const float* __restrict__ q1, const float* __restrict__ Wv2,
    const float* __restrict__ bv2, float* __restrict__ out)
{
    const int bt = blockIdx.x;
    __shared__ float qs_s[16][33];
    __shared__ float qw_s[16][33];
    __shared__ float hidp[4][16][64];
    __shared__ float wfb[16][64], b1b[16][64], vb[16][64];
    __shared__ float qt[16];

    const int t = threadIdx.x, w = t >> 6, lane = t & 63;
    const int quad = lane >> 4, l16 = lane & 15;
    const float bv2v = bv2[0];

    {
        int l = t * 2;
        float2 v = *(const float2*)&qs[(size_t)(bt * 16 + (l >> 5)) * NA + (l & 31)];
        qs_s[l >> 5][(l & 31) + 0] = v.x;
        qs_s[l >> 5][(l & 31) + 1] = v.y;
    }
    __syncthreads();

    const unsigned short* Yb = Ycn + (size_t)bt * NFRG * 256;

    // pass 1: hid with plain qs
    floatx4 hid[4];
    #pragma unroll
    for (int nf = 0; nf < 4; nf++) hid[nf] = (floatx4)0.f;
    for (int ia = 0; ia < 8; ia++) {
        const int a = w * 8 + ia;
        const unsigned short* yp = Yb + (size_t)(a * 4) * 256 + lane * 4;
        float qv[4];
        #pragma unroll
        for (int r = 0; r < 4; r++) qv[r] = qs_s[quad * 4 + r][a];
        #pragma unroll
        for (int nf = 0; nf < 4; nf++) {
            floatx4 c = bf4_to_f4(*(const ushort4*)(yp + nf * 256));   // c = -Y
            #pragma unroll
            for (int r = 0; r < 4; r++) hid[nf][r] += qv[r] * fabsf(c[r]);
        }
    }
    #pragma unroll
    for (int nf = 0; nf < 4; nf++)
        #pragma unroll
        for (int r = 0; r < 4; r++)
            hidp[w][quad * 4 + r][nf * 16 + l16] = hid[nf][r];

    // tail frags: 3 per wave
    #pragma unroll
    for (int fi = 0; fi < 3; fi++) {
        const int nft = w * 3 + fi;
        floatx4 c = bf4_to_f4(*(const ushort4*)(Yb + (size_t)(128 + nft) * 256 + lane * 4));
        const int e = (nft & 3) * 16 + l16;
        #pragma unroll
        for (int r = 0; r < 4; r++) {
            int b = quad * 4 + r;
            if (nft < 4)      wfb[b][e] = fabsf(c[r]);
            else if (nft < 8) b1b[b][e] = -c[r];
            else              vb[b][e]  = fmaxf(-c[r], 0.f) * Wv2[e];
        }
    }
    __syncthreads();

    // q_tot for rows w*4..w*4+3
    #pragma unroll
    for (int bb = 0; bb < 4; bb++) {
        int b = w * 4 + bb;
        float h = hidp[0][b][lane] + hidp[1][b][lane]
                + hidp[2][b][lane] + hidp[3][b][lane] + b1b[b][lane];
        h = h > 0.f ? h : expm1f(h);
        float val = h * wfb[b][lane] + vb[b][lane];
        #pragma unroll
        for (int off = 32; off > 0; off >>= 1) val += __shfl_xor(val, off);
        if (lane == 0) qt[b] = val + bv2v;
    }
    __syncthreads();

    // wc: thread (w,quad,l16) -> row rr = w*4+quad, agents 2*l16, 2*l16+1
    {
        const int rr = w * 4 + quad;
        float qtv = qt[rr];
        float d0 = fabsf(qtv - q1[(size_t)(2 * l16 + 0) * BT + bt * 16 + rr]);
        float d1 = fabsf(qtv - q1[(size_t)(2 * l16 + 1) * BT + bt * 16 + rr]);
        float ss = d0 * d0 + d1 * d1;
        ss += __shfl_xor(ss, 1); ss += __shfl_xor(ss, 2);
        ss += __shfl_xor(ss, 4); ss += __shfl_xor(ss, 8);
        float inv = 1.f / fmaxf(sqrtf(ss), 1e-12f);
        qw_s[rr][2 * l16 + 0] = qs_s[rr][2 * l16 + 0] * d0 * inv;
        qw_s[rr][2 * l16 + 1] = qs_s[rr][2 * l16 + 1] * d1 * inv;
    }
    __syncthreads();

    // pass 2: hid with qs*wc
    floatx4 hid2[4];
    #pragma unroll
    for (int nf = 0; nf < 4; nf++) hid2[nf] = (floatx4)0.f;
    for (int ia = 0; ia < 8; ia++) {
        const int a = w * 8 + ia;
        const unsigned short* yp = Yb + (size_t)(a * 4) * 256 + lane * 4;
        float qv[4];
        #pragma unroll
        for (int r = 0; r < 4; r++) qv[r] = qw_s[quad * 4 + r][a];
        #pragma unroll
        for (int nf = 0; nf < 4; nf++) {
            floatx4 c = bf4_to_f4(*(const ushort4*)(yp + nf * 256));
            #pragma unroll
            for (int r = 0; r < 4; r++) hid2[nf][r] += qv[r] * fabsf(c[r]);
        }
    }
    #pragma unroll
    for (int nf = 0; nf < 4; nf++)
        #pragma unroll
        for (int r = 0; r < 4; r++)
            hidp[w][quad * 4 + r][nf * 16 + l16] = hid2[nf][r];
    __syncthreads();

    #pragma unroll
    for (int bb = 0; bb < 4; bb++) {
        int b = w * 4 + bb;
        float h = hidp[0][b][lane] + hidp[1][b][lane]
                + hidp[2][b][lane] + hidp[3][b][lane] + b1b[b][lane];
        h = h > 0.f ? h : expm1f(h);
        float val = h * wfb[b][lane] + vb[b][lane];
        #pragma unroll
        for (int off = 32; off > 0; off >>= 1) val += __shfl_xor(val, off);
        if (lane == 0) out[bt * 16 + b] = val + bv2v;
    }
}

extern "C" void kernel_launch(void* const* d_in, const int* in_sizes, int n_in,
                              void* d_out, int out_size, void* d_ws, size_t ws_size,
                              hipStream_t stream) {
    const float* qs  = (const float*)d_in[0];
    const float* st  = (const float*)d_in[1];
    const float* Ww1 = (const float*)d_in[2];
    const float* bw1 = (const float*)d_in[3];
    const float* Wwf = (const float*)d_in[4];
    const float* bwf = (const float*)d_in[5];
    const float* Wb1 = (const float*)d_in[6];
    const float* bb1 = (const float*)d_in[7];
    const float* Wv1 = (const float*)d_in[8];
    const float* bv1 = (const float*)d_in[9];
    const float* Wv2 = (const float*)d_in[10];
    const float* bv2 = (const float*)d_in[11];
    float* out = (float*)d_out;

    // workspace (~28 MB)
    unsigned short* Ycn  = (unsigned short*)d_ws;                  // 128*144*256 bf16 = 9.44 MB
    unsigned short* stA  = Ycn + (size_t)128 * NFRG * 256;         // 8.39 MB
    unsigned short* Wswz = stA + (size_t)SD * SD;                  // 32*144*1024 bf16 = 9.44 MB
    float* bcat          = (float*)(Wswz + (size_t)32 * NFRG * 1024); // 2304 f32
    float* q1v           = bcat + NFRG * 16;                       // 32*2048 f32

    k0_ast <<<dim3(16, 128), 256, 0, stream>>>(st, stA);
    k0_wswz<<<dim3(NFRG / 2, 32), 256, 0, stream>>>(Ww1, Wwf, Wb1, Wv1, Wswz);
    k0_bias<<<(NFRG * 16 + 255) / 256, 256, 0, stream>>>(bw1, bwf, bb1, bv1, bcat);

    k1_gemm<<<dim3(BT / 64, NFRG / 8), 256, 0, stream>>>(stA, Wswz, bcat, Ycn);
    k3_q1  <<<dim3(BT / 16, NA), 64, 0, stream>>>(stA, qs, Wswz, Wv2, bv2, Ycn, q1v);
    k4_final<<<BT / 16, 256, 0, stream>>>(qs, Ycn, q1v, Wv2, bv2, out);
}

// Round 10
// 213.356 us; speedup vs baseline: 1.2138x; 1.0864x over previous
//
#include <hip/hip_runtime.h>
#include <math.h>
#include <stdint.h>

#define NA 32          // N_AGENTS
#define SD 2048        // STATE_DIM
#define BT 2048        // B = BS*T
#define NFRG 144       // col frags (2304 padded cols / 16); 128 agent + 12 tail + 4 pad

typedef float floatx4 __attribute__((ext_vector_type(4)));
typedef short bf16x8  __attribute__((ext_vector_type(8)));

__device__ __forceinline__ unsigned short f2bf(float f) {
    union { float f; uint32_t u; } v; v.f = f;
    uint32_t r = v.u + 0x7FFFu + ((v.u >> 16) & 1u);
    return (unsigned short)(r >> 16);
}

// ---- fragment layouts ----
// A-frag (stA):  elem((bt*64+kc)*512 + (quad*16+l16)*8 + j) = st[bt*16+l16][kc*32+quad*8+j]
// B-frag (Wswz): elem(((i*NFRG+f)*2+h)*512 + (quad*16+l16)*8 + j) = W[n=f*16+l16][k=i*64+h*32+quad*8+j]
// C-frag (Ycn, f32): elem((bt*NFRG+f)*256 + (quad*16+l16)*4 + r) = -Y[bt*16+quad*4+r][f*16+l16]

// ---------------- K0a: st -> A-fragment-order bf16 (coalesced writes) ----
__global__ __launch_bounds__(256) void k0_ast(const float* __restrict__ st,
                                              unsigned short* __restrict__ stA) {
    const int t  = threadIdx.x;
    const int kc = blockIdx.x * 4 + (t >> 6);   // 0..63
    const int bt = blockIdx.y;                  // 0..127
    const int l  = t & 63;
    const int quad = l >> 4, l16 = l & 15;
    const float* src = st + (size_t)(bt * 16 + l16) * SD + kc * 32 + quad * 8;
    float4 v0 = *(const float4*)(src);
    float4 v1 = *(const float4*)(src + 4);
    ushort4 o0, o1;
    o0.x = f2bf(v0.x); o0.y = f2bf(v0.y); o0.z = f2bf(v0.z); o0.w = f2bf(v0.w);
    o1.x = f2bf(v1.x); o1.y = f2bf(v1.y); o1.z = f2bf(v1.z); o1.w = f2bf(v1.w);
    unsigned short* dst = stA + ((size_t)bt * 64 + kc) * 512 + l * 8;
    *(ushort4*)(dst)     = o0;
    *(ushort4*)(dst + 4) = o1;
}

// ---------------- K0b: weights -> B-frag order (coalesced writes) --------
__global__ __launch_bounds__(256) void k0_wswz(const float* __restrict__ Ww1,
                                               const float* __restrict__ Wwf,
                                               const float* __restrict__ Wb1,
                                               const float* __restrict__ Wv1,
                                               unsigned short* __restrict__ Wswz) {
    const int t = threadIdx.x;
    const int i = blockIdx.y;                   // k-chunk 0..31
    const int f = blockIdx.x * 2 + (t >> 7);    // frag 0..143
    const int h = (t >> 6) & 1;
    const int l = t & 63;
    const int quad = l >> 4, l16 = l & 15;
    const int n = f * 16 + l16;

    const float* src; int ld, nr = 0;
    if (f < 128)      { src = Ww1; ld = 2048; nr = n; }
    else if (f < 132) { src = Wwf; ld = 64;   nr = n - 2048; }
    else if (f < 136) { src = Wb1; ld = 64;   nr = n - 2112; }
    else if (f < 140) { src = Wv1; ld = 64;   nr = n - 2176; }
    else              { src = nullptr; ld = 64; }

    const int k0 = i * 64 + h * 32 + quad * 8;
    unsigned short vals[8];
    #pragma unroll
    for (int j = 0; j < 8; j++)
        vals[j] = src ? f2bf(src[(size_t)(k0 + j) * ld + nr]) : (unsigned short)0;

    unsigned short* dst = Wswz + (((size_t)i * NFRG + f) * 2 + h) * 512 + l * 8;
    ushort4 o0 = {vals[0], vals[1], vals[2], vals[3]};
    ushort4 o1 = {vals[4], vals[5], vals[6], vals[7]};
    *(ushort4*)(dst)     = o0;
    *(ushort4*)(dst + 4) = o1;
}

// ---------------- K0c: concat bias (padded) ----------------
__global__ void k0_bias(const float* __restrict__ bw1, const float* __restrict__ bwf,
                        const float* __restrict__ bb1, const float* __restrict__ bv1,
                        float* __restrict__ bcat) {
    int n = blockIdx.x * 256 + threadIdx.x;
    if (n >= NFRG * 16) return;
    float v = 0.f;
    if (n < 2048)      v = bw1[n];
    else if (n < 2112) v = bwf[n - 2048];
    else if (n < 2176) v = bb1[n - 2112];
    else if (n < 2240) v = bv1[n - 2176];
    bcat[n] = v;
}

// ---------------- K1: Ycn = -(st @ Wcat + bias), fp32 fragment layout -----
// Register-streamed MFMA loop, software-pipelined one iteration.
__global__ __launch_bounds__(256) void k1_gemm(const unsigned short* __restrict__ stA,
                                               const unsigned short* __restrict__ Wswz,
                                               const float* __restrict__ bcat,
                                               float* __restrict__ Ycn)
{
    const int t = threadIdx.x;
    const int m0t = blockIdx.x * 4;   // btile base (64 rows)
    const int n0f = blockIdx.y * 8;   // frag base (128 cols)
    const int wid = t >> 6, lane = t & 63;
    const int wm = wid & 1, wn = wid >> 1;
    const int l16 = lane & 15;

    floatx4 acc[2][4];
    #pragma unroll
    for (int i = 0; i < 2; i++)
        #pragma unroll
        for (int j = 0; j < 4; j++) acc[i][j] = (floatx4)0.f;

    const unsigned short* Ap0 = stA + ((size_t)(m0t + wm * 2 + 0) * 64) * 512 + lane * 8;
    const unsigned short* Ap1 = stA + ((size_t)(m0t + wm * 2 + 1) * 64) * 512 + lane * 8;
    const unsigned short* Bbase = Wswz + ((size_t)(n0f + wn * 4) * 2) * 512 + lane * 8;

    bf16x8 a0c = *(const bf16x8*)(Ap0);
    bf16x8 a1c = *(const bf16x8*)(Ap1);
    bf16x8 bc[4];
    #pragma unroll
    for (int nf = 0; nf < 4; nf++)
        bc[nf] = *(const bf16x8*)(Bbase + (size_t)nf * 1024);

    for (int kc = 0; kc < 64; kc++) {
        bf16x8 a0n, a1n, bn[4];
        if (kc < 63) {
            const int kn = kc + 1;
            a0n = *(const bf16x8*)(Ap0 + (size_t)kn * 512);
            a1n = *(const bf16x8*)(Ap1 + (size_t)kn * 512);
            const unsigned short* Bp =
                Bbase + ((size_t)(kn >> 1) * NFRG * 2 + (kn & 1)) * 512;
            #pragma unroll
            for (int nf = 0; nf < 4; nf++)
                bn[nf] = *(const bf16x8*)(Bp + (size_t)nf * 1024);
        }
        #pragma unroll
        for (int nf = 0; nf < 4; nf++) {
            acc[0][nf] = __builtin_amdgcn_mfma_f32_16x16x32_bf16(a0c, bc[nf], acc[0][nf], 0, 0, 0);
            acc[1][nf] = __builtin_amdgcn_mfma_f32_16x16x32_bf16(a1c, bc[nf], acc[1][nf], 0, 0, 0);
        }
        a0c = a0n; a1c = a1n;
        #pragma unroll
        for (int nf = 0; nf < 4; nf++) bc[nf] = bn[nf];
    }

    #pragma unroll
    for (int mf = 0; mf < 2; mf++)
        #pragma unroll
        for (int nf = 0; nf < 4; nf++) {
            const int f  = n0f + wn * 4 + nf;
            const int bt = m0t + wm * 2 + mf;
            const float bias = bcat[f * 16 + l16];
            floatx4 o;
            #pragma unroll
            for (int r = 0; r < 4; r++) o[r] = -(acc[mf][nf][r] + bias);
            *(floatx4*)(Ycn + ((size_t)bt * NFRG + f) * 256 + lane * 4) = o;
        }
}

// ---------------- K3: q1[i][b] — single wave, XCD-swizzled, W-prefetch ---
// grid (x=i, y=bt): XCD = linear%8 = i%8 -> each XCD serves 4 masks
// (588 KB hot weights, L2-resident). fp32 Ycn loads go straight into the
// MFMA accumulator (no cvt chain). Weights prefetched one agent ahead.
__global__ __launch_bounds__(64) void k3_q1(
    const unsigned short* __restrict__ stA, const float* __restrict__ qs,
    const unsigned short* __restrict__ Wswz, const float* __restrict__ Wv2,
    const float* __restrict__ bv2, const float* __restrict__ Ycn,
    float* __restrict__ q1)
{
    const int i  = blockIdx.x;        // mask 0..31 (fast dim -> XCD = i%8)
    const int bt = blockIdx.y;        // b tile 0..127
    __shared__ float qs_s[16][33];

    const int t = threadIdx.x;        // == lane
    const int quad = t >> 4, l16 = t & 15;

    {
        int b = t >> 2, a0 = (t & 3) * 8;
        const float* src = qs + (size_t)(bt * 16 + b) * NA + a0;
        #pragma unroll
        for (int u = 0; u < 8; u++) qs_s[b][a0 + u] = src[u];
    }
    bf16x8 A0 = *(const bf16x8*)(stA + ((size_t)bt * 64 + 2 * i + 0) * 512 + t * 8);
    bf16x8 A1 = *(const bf16x8*)(stA + ((size_t)bt * 64 + 2 * i + 1) * 512 + t * 8);
    __syncthreads();

    floatx4 hid[4];
    #pragma unroll
    for (int nf = 0; nf < 4; nf++) hid[nf] = (floatx4)0.f;

    const float*          Yb = Ycn  + (size_t)bt * NFRG * 256;
    const unsigned short* Wb = Wswz + (size_t)i * NFRG * 1024;

    bf16x8 wc_[8];
    {
        const unsigned short* wp = Wb + t * 8;
        #pragma unroll
        for (int nf = 0; nf < 4; nf++) {
            wc_[nf * 2 + 0] = *(const bf16x8*)(wp + (size_t)nf * 1024);
            wc_[nf * 2 + 1] = *(const bf16x8*)(wp + (size_t)nf * 1024 + 512);
        }
    }

    for (int a = 0; a < 32; a++) {
        bf16x8 wn_[8];
        if (a < 31) {
            const unsigned short* wp = Wb + (size_t)((a + 1) * 4) * 1024 + t * 8;
            #pragma unroll
            for (int nf = 0; nf < 4; nf++) {
                wn_[nf * 2 + 0] = *(const bf16x8*)(wp + (size_t)nf * 1024);
                wn_[nf * 2 + 1] = *(const bf16x8*)(wp + (size_t)nf * 1024 + 512);
            }
        }
        const float* yp = Yb + (size_t)(a * 4) * 256 + t * 4;
        floatx4 acc[4];
        #pragma unroll
        for (int nf = 0; nf < 4; nf++) acc[nf] = *(const floatx4*)(yp + nf * 256);
        #pragma unroll
        for (int nf = 0; nf < 4; nf++) {
            acc[nf] = __builtin_amdgcn_mfma_f32_16x16x32_bf16(A0, wc_[nf*2+0], acc[nf], 0, 0, 0);
            acc[nf] = __builtin_amdgcn_mfma_f32_16x16x32_bf16(A1, wc_[nf*2+1], acc[nf], 0, 0, 0);
        }
        float qv[4];
        #pragma unroll
        for (int r = 0; r < 4; r++) qv[r] = qs_s[quad * 4 + r][a];
        #pragma unroll
        for (int nf = 0; nf < 4; nf++)
            #pragma unroll
            for (int r = 0; r < 4; r++)
                hid[nf][r] += qv[r] * fabsf(acc[nf][r]);
        #pragma unroll
        for (int u = 0; u < 8; u++) wc_[u] = wn_[u];
    }

    // tail frags 128..139: wf(0-3) | b1(4-7) | v(8-11)
    floatx4 wff[4], b1f[4], vacc = (floatx4)0.f;
    #pragma unroll
    for (int nft = 0; nft < 12; nft++) {
        const int f = 128 + nft;
        floatx4 c = *(const floatx4*)(Yb + (size_t)f * 256 + t * 4);
        const unsigned short* wp = Wb + (size_t)f * 1024 + t * 8;
        c = __builtin_amdgcn_mfma_f32_16x16x32_bf16(A0, *(const bf16x8*)(wp),       c, 0, 0, 0);
        c = __builtin_amdgcn_mfma_f32_16x16x32_bf16(A1, *(const bf16x8*)(wp + 512), c, 0, 0, 0);
        if (nft < 4) {
            #pragma unroll
            for (int r = 0; r < 4; r++) wff[nft][r] = fabsf(c[r]);
        } else if (nft < 8) {
            #pragma unroll
            for (int r = 0; r < 4; r++) b1f[nft - 4][r] = -c[r];
        } else {
            float wv2 = Wv2[(nft - 8) * 16 + l16];
            #pragma unroll
            for (int r = 0; r < 4; r++) vacc[r] += fmaxf(-c[r], 0.f) * wv2;
        }
    }

    const float bv2v = bv2[0];
    #pragma unroll
    for (int r = 0; r < 4; r++) {
        float s = vacc[r];
        #pragma unroll
        for (int nf = 0; nf < 4; nf++) {
            float h = hid[nf][r] + b1f[nf][r];
            h = h > 0.f ? h : expm1f(h);
            s += h * wff[nf][r];
        }
        s += __shfl_xor(s, 1); s += __shfl_xor(s, 2);
        s += __shfl_xor(s, 4); s += __shfl_xor(s, 8);
        if (l16 == 0) q1[(size_t)i * BT + bt * 16 + quad * 4 + r] = s + bv2v;
    }
}

// ---------------- K4: q_tot, wc, final mix — fp32 fragment consumer ------
__global__ __launch_bounds__(256) void k4_final(
    const float* __restrict__ qs, const float* __restrict__ Ycn,
    const float* __restrict__ q1, const float* __restrict__ Wv2,
    const float* __restrict__ bv2, float* __restrict__ out)
{
    const int bt = blockIdx.x;
    __shared__ float qs_s[16][33];
    __shared__ float qw_s[16][33];
    __shared__ float hidp[4][16][64];
    __shared__ float wfb[16][64], b1b[16][64], vb[16][64];
    __shared__ float qt[16];

    const int t = threadIdx.x, w = t >> 6, lane = t & 63;
    const int quad = lane >> 4, l16 = lane & 15;
    const float bv2v = bv2[0];

    {
        int l = t * 2;
        float2 v = *(const float2*)&qs[(size_t)(bt * 16 + (l >> 5)) * NA + (l & 31)];
        qs_s[l >> 5][(l & 31) + 0] = v.x;
        qs_s[l >> 5][(l & 31) + 1] = v.y;
    }
    __syncthreads();

    const float* Yb = Ycn + (size_t)bt * NFRG * 256;

    // pass 1: hid with plain qs
    floatx4 hid[4];
    #pragma unroll
    for (int nf = 0; nf < 4; nf++) hid[nf] = (floatx4)0.f;
    for (int ia = 0; ia < 8; ia++) {
        const int a = w * 8 + ia;
        const float* yp = Yb + (size_t)(a * 4) * 256 + lane * 4;
        float qv[4];
        #pragma unroll
        for (int r = 0; r < 4; r++) qv[r] = qs_s[quad * 4 + r][a];
        #pragma unroll
        for (int nf = 0; nf < 4; nf++) {
            floatx4 c = *(const floatx4*)(yp + nf * 256);   // c = -Y
            #pragma unroll
            for (int r = 0; r < 4; r++) hid[nf][r] += qv[r] * fabsf(c[r]);
        }
    }
    #pragma unroll
    for (int nf = 0; nf < 4; nf++)
        #pragma unroll
        for (int r = 0; r < 4; r++)
            hidp[w][quad * 4 + r][nf * 16 + l16] = hid[nf][r];

    // tail frags: 3 per wave
    #pragma unroll
    for (int fi = 0; fi < 3; fi++) {
        const int nft = w * 3 + fi;
        floatx4 c = *(const floatx4*)(Yb + (size_t)(128 + nft) * 256 + lane * 4);
        const int e = (nft & 3) * 16 + l16;
        #pragma unroll
        for (int r = 0; r < 4; r++) {
            int b = quad * 4 + r;
            if (nft < 4)      wfb[b][e] = fabsf(c[r]);
            else if (nft < 8) b1b[b][e] = -c[r];
            else              vb[b][e]  = fmaxf(-c[r], 0.f) * Wv2[e];
        }
    }
    __syncthreads();

    // q_tot for rows w*4..w*4+3
    #pragma unroll
    for (int bb = 0; bb < 4; bb++) {
        int b = w * 4 + bb;
        float h = hidp[0][b][lane] + hidp[1][b][lane]
                + hidp[2][b][lane] + hidp[3][b][lane] + b1b[b][lane];
        h = h > 0.f ? h : expm1f(h);
        float val = h * wfb[b][lane] + vb[b][lane];
        #pragma unroll
        for (int off = 32; off > 0; off >>= 1) val += __shfl_xor(val, off);
        if (lane == 0) qt[b] = val + bv2v;
    }
    __syncthreads();

    // wc: thread (w,quad,l16) -> row rr = w*4+quad, agents 2*l16, 2*l16+1
    {
        const int rr = w * 4 + quad;
        float qtv = qt[rr];
        float d0 = fabsf(qtv - q1[(size_t)(2 * l16 + 0) * BT + bt * 16 + rr]);
        float d1 = fabsf(qtv - q1[(size_t)(2 * l16 + 1) * BT + bt * 16 + rr]);
        float ss = d0 * d0 + d1 * d1;
        ss += __shfl_xor(ss, 1); ss += __shfl_xor(ss, 2);
        ss += __shfl_xor(ss, 4); ss += __shfl_xor(ss, 8);
        float inv = 1.f / fmaxf(sqrtf(ss), 1e-12f);
        qw_s[rr][2 * l16 + 0] = qs_s[rr][2 * l16 + 0] * d0 * inv;
        qw_s[rr][2 * l16 + 1] = qs_s[rr][2 * l16 + 1] * d1 * inv;
    }
    __syncthreads();

    // pass 2: hid with qs*wc
    floatx4 hid2[4];
    #pragma unroll
    for (int nf = 0; nf < 4; nf++) hid2[nf] = (floatx4)0.f;
    for (int ia = 0; ia < 8; ia++) {
        const int a = w * 8 + ia;
        const float* yp = Yb + (size_t)(a * 4) * 256 + lane * 4;
        float qv[4];
        #pragma unroll
        for (int r = 0; r < 4; r++) qv[r] = qw_s[quad * 4 + r][a];
        #pragma unroll
        for (int nf = 0; nf < 4; nf++) {
            floatx4 c = *(const floatx4*)(yp + nf * 256);
            #pragma unroll
            for (int r = 0; r < 4; r++) hid2[nf][r] += qv[r] * fabsf(c[r]);
        }
    }
    #pragma unroll
    for (int nf = 0; nf < 4; nf++)
        #pragma unroll
        for (int r = 0; r < 4; r++)
            hidp[w][quad * 4 + r][nf * 16 + l16] = hid2[nf][r];
    __syncthreads();

    #pragma unroll
    for (int bb = 0; bb < 4; bb++) {
        int b = w * 4 + bb;
        float h = hidp[0][b][lane] + hidp[1][b][lane]
                + hidp[2][b][lane] + hidp[3][b][lane] + b1b[b][lane];
        h = h > 0.f ? h : expm1f(h);
        float val = h * wfb[b][lane] + vb[b][lane];
        #pragma unroll
        for (int off = 32; off > 0; off >>= 1) val += __shfl_xor(val, off);
        if (lane == 0) out[bt * 16 + b] = val + bv2v;
    }
}

extern "C" void kernel_launch(void* const* d_in, const int* in_sizes, int n_in,
                              void* d_out, int out_size, void* d_ws, size_t ws_size,
                              hipStream_t stream) {
    const float* qs  = (const float*)d_in[0];
    const float* st  = (const float*)d_in[1];
    const float* Ww1 = (const float*)d_in[2];
    const float* bw1 = (const float*)d_in[3];
    const float* Wwf = (const float*)d_in[4];
    const float* bwf = (const float*)d_in[5];
    const float* Wb1 = (const float*)d_in[6];
    const float* bb1 = (const float*)d_in[7];
    const float* Wv1 = (const float*)d_in[8];
    const float* bv1 = (const float*)d_in[9];
    const float* Wv2 = (const float*)d_in[10];
    const float* bv2 = (const float*)d_in[11];
    float* out = (float*)d_out;

    // workspace (~37 MB, same footprint as proven R3-R7 layout)
    float* Ycn           = (float*)d_ws;                           // 128*144*256 f32 = 18.87 MB
    unsigned short* stA  = (unsigned short*)(Ycn + (size_t)128 * NFRG * 256); // 8.39 MB
    unsigned short* Wswz = stA + (size_t)SD * SD;                  // 32*144*1024 bf16 = 9.44 MB
    float* bcat          = (float*)(Wswz + (size_t)32 * NFRG * 1024); // 2304 f32
    float* q1v           = bcat + NFRG * 16;                       // 32*2048 f32

    k0_ast <<<dim3(16, 128), 256, 0, stream>>>(st, stA);
    k0_wswz<<<dim3(NFRG / 2, 32), 256, 0, stream>>>(Ww1, Wwf, Wb1, Wv1, Wswz);
    k0_bias<<<(NFRG * 16 + 255) / 256, 256, 0, stream>>>(bw1, bwf, bb1, bv1, bcat);

    k1_gemm<<<dim3(BT / 64, NFRG / 8), 256, 0, stream>>>(stA, Wswz, bcat, Ycn);
    k3_q1  <<<dim3(NA, BT / 16), 64, 0, stream>>>(stA, qs, Wswz, Wv2, bv2, Ycn, q1v);
    k4_final<<<BT / 16, 256, 0, stream>>>(qs, Ycn, q1v, Wv2, bv2, out);
}